// Round 1
// baseline (511.398 us; speedup 1.0000x reference)
//
#include <hip/hip_runtime.h>
#include <hip/hip_bf16.h>

// 2-layer GCN, N=50000, E=800000, D_IN=256, H=256, D_OUT=128.
// Round 5: XCD-pinned feature-chunked gather (chunk-major h, L2-resident
// per-XCD working set), recompute edge weights from L2-resident dinv,
// parallel 3-phase scan. GEMMs unchanged except chunk-major epilogue.

typedef __attribute__((ext_vector_type(8))) short bf16x8;
typedef __attribute__((ext_vector_type(4))) float f32x4;

__device__ inline float bf2f(unsigned short u) {
    return __uint_as_float(((unsigned)u) << 16);
}
__device__ inline unsigned short f2bf(float f) {
    unsigned x = __float_as_uint(f);
    unsigned r = (x + 0x7fffu + ((x >> 16) & 1u)) >> 16;   // RNE
    return (unsigned short)r;
}

// ---------------- degree / dinv ----------------
__global__ void degree_kernel(const int* __restrict__ dst, unsigned* __restrict__ deg, int E) {
    int e = blockIdx.x * blockDim.x + threadIdx.x;
    if (e < E) atomicAdd(&deg[dst[e]], 1u);
}

__global__ void dinv_kernel(const unsigned* __restrict__ deg, float* __restrict__ dinv, int N) {
    int i = blockIdx.x * blockDim.x + threadIdx.x;
    if (i < N) dinv[i] = rsqrtf((float)(deg[i] + 1u));  // +1 self-loop
}

// ---------------- parallel 3-phase exclusive scan ----------------
#define SCAN_CHUNK 2048

__global__ __launch_bounds__(256) void scan_phase1(const unsigned* __restrict__ deg,
                                                   int* __restrict__ bsum, int N) {
    __shared__ int ws[4];
    const int t = threadIdx.x, lane = t & 63, w = t >> 6;
    int base = blockIdx.x * SCAN_CHUNK;
    int s = 0;
#pragma unroll
    for (int r = 0; r < SCAN_CHUNK / 256; r++) {
        int i = base + r * 256 + t;
        s += (i < N) ? (int)deg[i] : 0;
    }
#pragma unroll
    for (int off = 1; off < 64; off <<= 1) s += __shfl_xor(s, off, 64);
    if (lane == 0) ws[w] = s;
    __syncthreads();
    if (t == 0) bsum[blockIdx.x] = ws[0] + ws[1] + ws[2] + ws[3];
}

__global__ void scan_phase2(int* __restrict__ bsum, int nb) {
    // one wave; serial over 64-batches with carry
    const int t = threadIdx.x;
    int carry = 0;
    for (int b = 0; b < nb; b += 64) {
        int i = b + t;
        int v = (i < nb) ? bsum[i] : 0;
        int x = v;
#pragma unroll
        for (int off = 1; off < 64; off <<= 1) {
            int y = __shfl_up(x, off, 64);
            if (t >= off) x += y;
        }
        if (i < nb) bsum[i] = carry + x - v;   // exclusive
        carry += __shfl(x, 63, 64);
    }
}

__global__ __launch_bounds__(256) void scan_phase3(const unsigned* __restrict__ deg,
                                                   const int* __restrict__ bsum,
                                                   int* __restrict__ rowptr,
                                                   int* __restrict__ cursor, int N) {
    __shared__ int ws[4];
    const int t = threadIdx.x, lane = t & 63, w = t >> 6;
    int base = blockIdx.x * SCAN_CHUNK;
    int carry = bsum[blockIdx.x];
#pragma unroll
    for (int r = 0; r < SCAN_CHUNK / 256; r++) {
        int i = base + r * 256 + t;
        int v = (i < N) ? (int)deg[i] : 0;
        int x = v;
#pragma unroll
        for (int off = 1; off < 64; off <<= 1) {
            int y = __shfl_up(x, off, 64);
            if (lane >= off) x += y;
        }
        if (lane == 63) ws[w] = x;
        __syncthreads();
        int wo = 0;
        for (int j = 0; j < w; j++) wo += ws[j];
        int excl = x + wo - v;
        if (i < N) { rowptr[i] = carry + excl; cursor[i] = carry + excl; }
        int total = ws[0] + ws[1] + ws[2] + ws[3];
        __syncthreads();
        carry += total;
    }
    if (blockIdx.x == gridDim.x - 1 && t == 0) rowptr[N] = carry;
}

// ---------------- CSR fill (col only; weights recomputed in gather) ------
__global__ __launch_bounds__(256) void fill_kernel(const int* __restrict__ src,
                                                   const int* __restrict__ dst,
                                                   int* __restrict__ cursor,
                                                   int* __restrict__ col, int E) {
    int e = blockIdx.x * blockDim.x + threadIdx.x;
    if (e < E) {
        int d = dst[e];
        int pos = atomicAdd(&cursor[d], 1);
        col[pos] = src[e];
    }
}

// ---------------- fp32 -> bf16 convert (x) ----------------
__global__ __launch_bounds__(256) void convert_x_kernel(const float* __restrict__ in,
                                                        unsigned short* __restrict__ out,
                                                        long n4) {
    long i = (long)blockIdx.x * blockDim.x + threadIdx.x;
    if (i < n4) {
        float4 v = ((const float4*)in)[i];
        ushort4 o;
        o.x = f2bf(v.x); o.y = f2bf(v.y); o.z = f2bf(v.z); o.w = f2bf(v.w);
        ((ushort4*)out)[i] = o;
    }
}

// ---------------- fp32 W[K][Nw] -> bf16 WT[Nw][K] ----------------
__global__ __launch_bounds__(256) void convert_wt_kernel(const float* __restrict__ W,
                                                         unsigned short* __restrict__ WT,
                                                         int K, int Nw) {
    int id = blockIdx.x * blockDim.x + threadIdx.x;
    if (id < K * Nw) {
        int k = id / Nw;
        int n = id % Nw;
        WT[(long)n * K + k] = f2bf(W[id]);
    }
}

// ---------------- bf16 MFMA GEMM: C = A[M,K] * BT[Nc,K]^T, chunk-major C --
// 128x128 tile, BK=64, 256 threads (4 waves), global_load_lds width-16
// staging, 16B-chunk XOR swizzle. C written as [Nc/CH][M][CH] bf16.
#define GBM 128
#define GBN 128
#define GBK 64
template <int CH>
__global__ __launch_bounds__(256) void gemm_bf16(const unsigned short* __restrict__ A,
                                                 const unsigned short* __restrict__ BT,
                                                 unsigned short* __restrict__ C,
                                                 int M, int Nc, int K) {
    __shared__ __align__(16) unsigned short As[GBM * GBK];
    __shared__ __align__(16) unsigned short Bs[GBN * GBK];
    const int t = threadIdx.x;
    const int lane = t & 63;
    const int w = t >> 6;
    const int row0 = blockIdx.x * GBM;
    const int col0 = blockIdx.y * GBN;
    const int rb = (w >> 1) * 64;    // wave row base in tile
    const int cb = (w & 1) * 64;     // wave col base in tile

    f32x4 acc[4][4] = {};

    for (int kb = 0; kb < K; kb += GBK) {
        // ---- stage A tile (128 rows x 64 k) : 1024 16B chunks ----
#pragma unroll
        for (int i = 0; i < 4; i++) {
            int p = i * 256 + t;
            int row = p >> 3;
            int slot = p & 7;
            int chunk = slot ^ (row & 7);
            int grow = row0 + row;
            if (grow >= M) grow = M - 1;          // clamp; garbage rows never stored
            const unsigned short* src = A + (size_t)grow * K + kb + chunk * 8;
            __builtin_amdgcn_global_load_lds(
                (const __attribute__((address_space(1))) void*)src,
                (__attribute__((address_space(3))) void*)&As[p * 8], 16, 0, 0);
        }
        // ---- stage B tile (128 n-rows x 64 k) ----
#pragma unroll
        for (int i = 0; i < 4; i++) {
            int p = i * 256 + t;
            int row = p >> 3;
            int slot = p & 7;
            int chunk = slot ^ (row & 7);
            const unsigned short* src = BT + (size_t)(col0 + row) * K + kb + chunk * 8;
            __builtin_amdgcn_global_load_lds(
                (const __attribute__((address_space(1))) void*)src,
                (__attribute__((address_space(3))) void*)&Bs[p * 8], 16, 0, 0);
        }
        asm volatile("s_waitcnt vmcnt(0)" ::: "memory");
        __syncthreads();

        // ---- compute: 2 k-steps of 32, 16 MFMAs each per wave ----
#pragma unroll
        for (int ks = 0; ks < 2; ks++) {
            int kq = ks * 4 + (lane >> 4);      // global 8-elem chunk index 0..7
            int rsel = lane & 15;
            bf16x8 af[4], bfr[4];
#pragma unroll
            for (int mt = 0; mt < 4; mt++) {
                int m = rb + mt * 16 + rsel;
                int slot = kq ^ (m & 7);
                af[mt] = *(const bf16x8*)&As[m * GBK + slot * 8];
            }
#pragma unroll
            for (int nt = 0; nt < 4; nt++) {
                int n = cb + nt * 16 + rsel;
                int slot = kq ^ (n & 7);
                bfr[nt] = *(const bf16x8*)&Bs[n * GBK + slot * 8];
            }
#pragma unroll
            for (int mt = 0; mt < 4; mt++)
#pragma unroll
                for (int nt = 0; nt < 4; nt++)
                    acc[mt][nt] = __builtin_amdgcn_mfma_f32_16x16x32_bf16(
                        af[mt], bfr[nt], acc[mt][nt], 0, 0, 0);
        }
        __syncthreads();
    }

    // ---- epilogue: chunk-major C[(gcol/CH)*M + g][gcol%CH] --------------
#pragma unroll
    for (int mt = 0; mt < 4; mt++) {
#pragma unroll
        for (int nt = 0; nt < 4; nt++) {
            int gcol = col0 + cb + nt * 16 + (lane & 15);
            int c = gcol / CH;
            int fo = gcol % CH;
            int grow0 = row0 + rb + mt * 16 + 4 * (lane >> 4);
#pragma unroll
            for (int r = 0; r < 4; r++) {
                int g = grow0 + r;
                if (g < M)
                    C[((size_t)c * M + g) * CH + fo] = f2bf(acc[mt][nt][r]);
            }
        }
    }
}

// ---------------- XCD-pinned chunk-major CSR pull-gather ------------------
// 1D grid: chunk = blockIdx.x % 8 (round-robin -> each XCD owns one chunk,
// whose h slab [N][CH] bf16 is L2-resident). Block = 256 threads = 4 waves,
// one node per wave. Within a wave: LF = CH/2 lanes cover the chunk's
// features (ushort2 each), 64/LF edge-groups walk the edge list in parallel;
// butterfly-reduce across edge groups at the end. Edge weight recomputed
// from L2-resident dinv (col is the only per-edge stream).
template <int CH, bool OUT_BF16>
__global__ __launch_bounds__(256) void gather_cm_kernel(
    const unsigned short* __restrict__ h_cm,   // [8][N][CH]
    const int* __restrict__ rowptr,
    const int* __restrict__ col,
    const float* __restrict__ dinv,
    const float* __restrict__ bias,
    void* __restrict__ out,                    // node-major [N][F]
    int Nn, int F) {
    const int bid = blockIdx.x;
    const int chunk = bid & 7;
    const int nb = bid >> 3;
    const int wv = threadIdx.x >> 6;
    const int lane = threadIdx.x & 63;
    const int node = nb * 4 + wv;
    if (node >= Nn) return;

    constexpr int LF = CH / 2;       // lanes per feature-group
    constexpr int NE = 64 / LF;      // parallel edge-groups
    const int fl = lane & (LF - 1);
    const int eg = lane / LF;

    const unsigned short* hc = h_cm + (size_t)chunk * Nn * CH;
    const int beg = rowptr[node];
    const int end = rowptr[node + 1];
    const float ddst = dinv[node];

    float a0 = 0.f, a1 = 0.f;
    int e = beg + eg;
    for (; e + NE < end; e += 2 * NE) {
        int s0 = col[e], s1 = col[e + NE];
        float w0 = dinv[s0] * ddst;
        float w1 = dinv[s1] * ddst;
        ushort2 u0 = *(const ushort2*)&hc[(size_t)s0 * CH + 2 * fl];
        ushort2 u1 = *(const ushort2*)&hc[(size_t)s1 * CH + 2 * fl];
        a0 += bf2f(u0.x) * w0 + bf2f(u1.x) * w1;
        a1 += bf2f(u0.y) * w0 + bf2f(u1.y) * w1;
    }
    if (e < end) {
        int s = col[e];
        float wv2 = dinv[s] * ddst;
        ushort2 u = *(const ushort2*)&hc[(size_t)s * CH + 2 * fl];
        a0 += bf2f(u.x) * wv2;
        a1 += bf2f(u.y) * wv2;
    }
#pragma unroll
    for (int off = LF; off < 64; off <<= 1) {
        a0 += __shfl_xor(a0, off, 64);
        a1 += __shfl_xor(a1, off, 64);
    }
    if (lane < LF) {
        int f0 = chunk * CH + 2 * fl;
        ushort2 us = *(const ushort2*)&hc[(size_t)node * CH + 2 * fl];
        float2 bv = *(const float2*)&bias[f0];
        float v0 = fmaxf(a0 + bf2f(us.x) * ddst * ddst + bv.x, 0.f);
        float v1 = fmaxf(a1 + bf2f(us.y) * ddst * ddst + bv.y, 0.f);
        if (OUT_BF16) {
            ushort2 o; o.x = f2bf(v0); o.y = f2bf(v1);
            *(ushort2*)&((unsigned short*)out)[(size_t)node * F + f0] = o;
        } else {
            float2 o; o.x = v0; o.y = v1;
            *(float2*)&((float*)out)[(size_t)node * F + f0] = o;
        }
    }
}

extern "C" void kernel_launch(void* const* d_in, const int* in_sizes, int n_in,
                              void* d_out, int out_size, void* d_ws, size_t ws_size,
                              hipStream_t stream) {
    const float* x  = (const float*)d_in[0];   // [N, 256]
    const int* ei   = (const int*)d_in[1];     // [2, E] int32
    const float* W1 = (const float*)d_in[2];   // [256, 256]
    const float* b1 = (const float*)d_in[3];   // [256]
    const float* W2 = (const float*)d_in[4];   // [256, 128]
    const float* b2 = (const float*)d_in[5];   // [128]

    const int DIN = 256;
    const int N = in_sizes[0] / DIN;        // 50000
    const int E = in_sizes[1] / 2;          // 800000
    const int H = in_sizes[3];              // 256
    const int DOUT = in_sizes[5];           // 128

    const int* src = ei;
    const int* dst = ei + E;

    // workspace layout (all blocks 16B-aligned for N=50000)
    char* ws = (char*)d_ws;
    unsigned* deg = (unsigned*)ws;                   ws += (size_t)N * 4;
    float* dinv   = (float*)ws;                      ws += (size_t)N * 4;
    int* rowptr   = (int*)ws;                        ws += (size_t)(N + 4) * 4;
    int* bsum     = (int*)ws;                        ws += 64 * 4;
    int* cursor   = (int*)ws;                        ws += (size_t)N * 4;
    int* col      = (int*)ws;                        ws += (size_t)E * 4;
    unsigned short* xb  = (unsigned short*)ws;       ws += (size_t)N * DIN * 2;
    unsigned short* w1t = (unsigned short*)ws;       ws += (size_t)DIN * H * 2;
    unsigned short* w2t = (unsigned short*)ws;       ws += (size_t)H * DOUT * 2;
    unsigned short* h1b = (unsigned short*)ws;       ws += (size_t)N * H * 2;    // chunk-major [8][N][32]
    unsigned short* y1b = (unsigned short*)ws;       ws += (size_t)N * H * 2;    // node-major [N][256]
    unsigned short* h2b = xb;                        // chunk-major [8][N][16]; xb dead after gemm1
    float* outp = (float*)d_out;

    // ---- CSR build ----
    hipMemsetAsync(deg, 0, (size_t)N * 4, stream);
    degree_kernel<<<(E + 255) / 256, 256, 0, stream>>>(dst, deg, E);
    dinv_kernel<<<(N + 255) / 256, 256, 0, stream>>>(deg, dinv, N);
    {
        int nb = (N + SCAN_CHUNK - 1) / SCAN_CHUNK;
        scan_phase1<<<nb, 256, 0, stream>>>(deg, bsum, N);
        scan_phase2<<<1, 64, 0, stream>>>(bsum, nb);
        scan_phase3<<<nb, 256, 0, stream>>>(deg, bsum, rowptr, cursor, N);
    }
    fill_kernel<<<(E + 255) / 256, 256, 0, stream>>>(src, dst, cursor, col, E);

    // ---- conversions ----
    {
        long n4 = (long)N * DIN / 4;
        convert_x_kernel<<<(int)((n4 + 255) / 256), 256, 0, stream>>>(x, xb, n4);
        convert_wt_kernel<<<(DIN * H + 255) / 256, 256, 0, stream>>>(W1, w1t, DIN, H);
        convert_wt_kernel<<<(H * DOUT + 255) / 256, 256, 0, stream>>>(W2, w2t, H, DOUT);
    }

    // ---- layer 1: h1 = x @ W1 (bf16 MFMA, chunk-major out CH=32) ----
    {
        dim3 grid((N + GBM - 1) / GBM, H / GBN);
        gemm_bf16<32><<<grid, 256, 0, stream>>>(xb, w1t, h1b, N, H, DIN);
    }
    gather_cm_kernel<32, true><<<8 * ((N + 3) / 4), 256, 0, stream>>>(
        h1b, rowptr, col, dinv, b1, y1b, N, H);

    // ---- layer 2: h2 = y1 @ W2 (bf16 MFMA, chunk-major out CH=16) ----
    {
        dim3 grid((N + GBM - 1) / GBM, DOUT / GBN);
        gemm_bf16<16><<<grid, 256, 0, stream>>>(y1b, w2t, h2b, N, DOUT, H);
    }
    gather_cm_kernel<16, false><<<8 * ((N + 3) / 4), 256, 0, stream>>>(
        h2b, rowptr, col, dinv, b2, outp, N, DOUT);
}

// Round 2
// 402.131 us; speedup vs baseline: 1.2717x; 1.2717x over previous
//
#include <hip/hip_runtime.h>
#include <hip/hip_bf16.h>

// 2-layer GCN, N=50000, E=800000, D_IN=256, H=256, D_OUT=128.
// Round 6: keep XCD-pinned chunk-major h (L2-resident slab per XCD), but
// restore the serial-edge-loop gather structure: LF lanes own one node's
// chunk features in-lane (no cross-lane reduce), unroll-4 edge loop gives
// 4 independent L2 loads in flight, ddst factored out of the loop.

typedef __attribute__((ext_vector_type(8))) short bf16x8;
typedef __attribute__((ext_vector_type(4))) float f32x4;

__device__ inline float bf2f(unsigned short u) {
    return __uint_as_float(((unsigned)u) << 16);
}
__device__ inline unsigned short f2bf(float f) {
    unsigned x = __float_as_uint(f);
    unsigned r = (x + 0x7fffu + ((x >> 16) & 1u)) >> 16;   // RNE
    return (unsigned short)r;
}

// ---------------- degree / dinv ----------------
__global__ void degree_kernel(const int* __restrict__ dst, unsigned* __restrict__ deg, int E) {
    int e = blockIdx.x * blockDim.x + threadIdx.x;
    if (e < E) atomicAdd(&deg[dst[e]], 1u);
}

__global__ void dinv_kernel(const unsigned* __restrict__ deg, float* __restrict__ dinv, int N) {
    int i = blockIdx.x * blockDim.x + threadIdx.x;
    if (i < N) dinv[i] = rsqrtf((float)(deg[i] + 1u));  // +1 self-loop
}

// ---------------- parallel 3-phase exclusive scan ----------------
#define SCAN_CHUNK 2048

__global__ __launch_bounds__(256) void scan_phase1(const unsigned* __restrict__ deg,
                                                   int* __restrict__ bsum, int N) {
    __shared__ int ws[4];
    const int t = threadIdx.x, lane = t & 63, w = t >> 6;
    int base = blockIdx.x * SCAN_CHUNK;
    int s = 0;
#pragma unroll
    for (int r = 0; r < SCAN_CHUNK / 256; r++) {
        int i = base + r * 256 + t;
        s += (i < N) ? (int)deg[i] : 0;
    }
#pragma unroll
    for (int off = 1; off < 64; off <<= 1) s += __shfl_xor(s, off, 64);
    if (lane == 0) ws[w] = s;
    __syncthreads();
    if (t == 0) bsum[blockIdx.x] = ws[0] + ws[1] + ws[2] + ws[3];
}

__global__ void scan_phase2(int* __restrict__ bsum, int nb) {
    const int t = threadIdx.x;
    int carry = 0;
    for (int b = 0; b < nb; b += 64) {
        int i = b + t;
        int v = (i < nb) ? bsum[i] : 0;
        int x = v;
#pragma unroll
        for (int off = 1; off < 64; off <<= 1) {
            int y = __shfl_up(x, off, 64);
            if (t >= off) x += y;
        }
        if (i < nb) bsum[i] = carry + x - v;   // exclusive
        carry += __shfl(x, 63, 64);
    }
}

__global__ __launch_bounds__(256) void scan_phase3(const unsigned* __restrict__ deg,
                                                   const int* __restrict__ bsum,
                                                   int* __restrict__ rowptr,
                                                   int* __restrict__ cursor, int N) {
    __shared__ int ws[4];
    const int t = threadIdx.x, lane = t & 63, w = t >> 6;
    int base = blockIdx.x * SCAN_CHUNK;
    int carry = bsum[blockIdx.x];
#pragma unroll
    for (int r = 0; r < SCAN_CHUNK / 256; r++) {
        int i = base + r * 256 + t;
        int v = (i < N) ? (int)deg[i] : 0;
        int x = v;
#pragma unroll
        for (int off = 1; off < 64; off <<= 1) {
            int y = __shfl_up(x, off, 64);
            if (lane >= off) x += y;
        }
        if (lane == 63) ws[w] = x;
        __syncthreads();
        int wo = 0;
        for (int j = 0; j < w; j++) wo += ws[j];
        int excl = x + wo - v;
        if (i < N) { rowptr[i] = carry + excl; cursor[i] = carry + excl; }
        int total = ws[0] + ws[1] + ws[2] + ws[3];
        __syncthreads();
        carry += total;
    }
    if (blockIdx.x == gridDim.x - 1 && t == 0) rowptr[N] = carry;
}

// ---------------- CSR fill (col only; weights recomputed in gather) ------
__global__ __launch_bounds__(256) void fill_kernel(const int* __restrict__ src,
                                                   const int* __restrict__ dst,
                                                   int* __restrict__ cursor,
                                                   int* __restrict__ col, int E) {
    int e = blockIdx.x * blockDim.x + threadIdx.x;
    if (e < E) {
        int d = dst[e];
        int pos = atomicAdd(&cursor[d], 1);
        col[pos] = src[e];
    }
}

// ---------------- fp32 -> bf16 convert (x) ----------------
__global__ __launch_bounds__(256) void convert_x_kernel(const float* __restrict__ in,
                                                        unsigned short* __restrict__ out,
                                                        long n4) {
    long i = (long)blockIdx.x * blockDim.x + threadIdx.x;
    if (i < n4) {
        float4 v = ((const float4*)in)[i];
        ushort4 o;
        o.x = f2bf(v.x); o.y = f2bf(v.y); o.z = f2bf(v.z); o.w = f2bf(v.w);
        ((ushort4*)out)[i] = o;
    }
}

// ---------------- fp32 W[K][Nw] -> bf16 WT[Nw][K] ----------------
__global__ __launch_bounds__(256) void convert_wt_kernel(const float* __restrict__ W,
                                                         unsigned short* __restrict__ WT,
                                                         int K, int Nw) {
    int id = blockIdx.x * blockDim.x + threadIdx.x;
    if (id < K * Nw) {
        int k = id / Nw;
        int n = id % Nw;
        WT[(long)n * K + k] = f2bf(W[id]);
    }
}

// ---------------- bf16 MFMA GEMM: C = A[M,K] * BT[Nc,K]^T, chunk-major C --
#define GBM 128
#define GBN 128
#define GBK 64
template <int CH>
__global__ __launch_bounds__(256) void gemm_bf16(const unsigned short* __restrict__ A,
                                                 const unsigned short* __restrict__ BT,
                                                 unsigned short* __restrict__ C,
                                                 int M, int Nc, int K) {
    __shared__ __align__(16) unsigned short As[GBM * GBK];
    __shared__ __align__(16) unsigned short Bs[GBN * GBK];
    const int t = threadIdx.x;
    const int lane = t & 63;
    const int w = t >> 6;
    const int row0 = blockIdx.x * GBM;
    const int col0 = blockIdx.y * GBN;
    const int rb = (w >> 1) * 64;
    const int cb = (w & 1) * 64;

    f32x4 acc[4][4] = {};

    for (int kb = 0; kb < K; kb += GBK) {
#pragma unroll
        for (int i = 0; i < 4; i++) {
            int p = i * 256 + t;
            int row = p >> 3;
            int slot = p & 7;
            int chunk = slot ^ (row & 7);
            int grow = row0 + row;
            if (grow >= M) grow = M - 1;          // clamp; garbage rows never stored
            const unsigned short* src = A + (size_t)grow * K + kb + chunk * 8;
            __builtin_amdgcn_global_load_lds(
                (const __attribute__((address_space(1))) void*)src,
                (__attribute__((address_space(3))) void*)&As[p * 8], 16, 0, 0);
        }
#pragma unroll
        for (int i = 0; i < 4; i++) {
            int p = i * 256 + t;
            int row = p >> 3;
            int slot = p & 7;
            int chunk = slot ^ (row & 7);
            const unsigned short* src = BT + (size_t)(col0 + row) * K + kb + chunk * 8;
            __builtin_amdgcn_global_load_lds(
                (const __attribute__((address_space(1))) void*)src,
                (__attribute__((address_space(3))) void*)&Bs[p * 8], 16, 0, 0);
        }
        asm volatile("s_waitcnt vmcnt(0)" ::: "memory");
        __syncthreads();

#pragma unroll
        for (int ks = 0; ks < 2; ks++) {
            int kq = ks * 4 + (lane >> 4);
            int rsel = lane & 15;
            bf16x8 af[4], bfr[4];
#pragma unroll
            for (int mt = 0; mt < 4; mt++) {
                int m = rb + mt * 16 + rsel;
                int slot = kq ^ (m & 7);
                af[mt] = *(const bf16x8*)&As[m * GBK + slot * 8];
            }
#pragma unroll
            for (int nt = 0; nt < 4; nt++) {
                int n = cb + nt * 16 + rsel;
                int slot = kq ^ (n & 7);
                bfr[nt] = *(const bf16x8*)&Bs[n * GBK + slot * 8];
            }
#pragma unroll
            for (int mt = 0; mt < 4; mt++)
#pragma unroll
                for (int nt = 0; nt < 4; nt++)
                    acc[mt][nt] = __builtin_amdgcn_mfma_f32_16x16x32_bf16(
                        af[mt], bfr[nt], acc[mt][nt], 0, 0, 0);
        }
        __syncthreads();
    }

    // epilogue: chunk-major C[(gcol/CH)*M + g][gcol%CH]
#pragma unroll
    for (int mt = 0; mt < 4; mt++) {
#pragma unroll
        for (int nt = 0; nt < 4; nt++) {
            int gcol = col0 + cb + nt * 16 + (lane & 15);
            int c = gcol / CH;
            int fo = gcol % CH;
            int grow0 = row0 + rb + mt * 16 + 4 * (lane >> 4);
#pragma unroll
            for (int r = 0; r < 4; r++) {
                int g = grow0 + r;
                if (g < M)
                    C[((size_t)c * M + g) * CH + fo] = f2bf(acc[mt][nt][r]);
            }
        }
    }
}

// ---------------- XCD-pinned chunk-major CSR pull-gather ------------------
// chunk = blockIdx.x & 7 -> round-robin pins each chunk's h slab ([N][CH]
// bf16, 3.2/1.6 MB) to one XCD's L2. Within a block (256 thr = 4 waves):
// LF = CH/2 lanes own one node's chunk features (ushort2 each, 64B
// coalesced row reads), NS = 64/LF node-slots per wave. Serial unroll-4
// edge loop per node: 4 independent L2 loads in flight, features stay
// in-lane (no cross-lane reduce), ddst factored out of the loop. Edge
// weight recomputed from L2-resident dinv (col is the only edge stream).
template <int CH, bool OUT_BF16>
__global__ __launch_bounds__(256) void gather_cm_kernel(
    const unsigned short* __restrict__ h_cm,   // [8][N][CH]
    const int* __restrict__ rowptr,
    const int* __restrict__ col,
    const float* __restrict__ dinv,
    const float* __restrict__ bias,
    void* __restrict__ out,                    // node-major [N][F]
    int Nn, int F) {
    constexpr int LF = CH / 2;       // lanes per node
    constexpr int NS = 64 / LF;      // node slots per wave
    constexpr int NPB = NS * 4;      // nodes per block
    const int chunk = blockIdx.x & 7;
    const int g = blockIdx.x >> 3;
    const int w = threadIdx.x >> 6;
    const int lane = threadIdx.x & 63;
    const int fl = lane & (LF - 1);
    const int ns = lane / LF;
    const int node = g * NPB + w * NS + ns;
    const bool valid = node < Nn;
    const int nc = valid ? node : Nn - 1;

    const unsigned short* hc = h_cm + (size_t)chunk * Nn * CH;
    const int beg = rowptr[nc];
    const int end = valid ? rowptr[nc + 1] : beg;
    const float ddst = dinv[nc];

    float a0 = 0.f, a1 = 0.f;
    int e = beg;
    for (; e + 4 <= end; e += 4) {
        int s0 = col[e], s1 = col[e + 1], s2 = col[e + 2], s3 = col[e + 3];
        float w0 = dinv[s0], w1 = dinv[s1], w2 = dinv[s2], w3 = dinv[s3];
        ushort2 u0 = *(const ushort2*)&hc[(size_t)s0 * CH + 2 * fl];
        ushort2 u1 = *(const ushort2*)&hc[(size_t)s1 * CH + 2 * fl];
        ushort2 u2 = *(const ushort2*)&hc[(size_t)s2 * CH + 2 * fl];
        ushort2 u3 = *(const ushort2*)&hc[(size_t)s3 * CH + 2 * fl];
        a0 += bf2f(u0.x) * w0 + bf2f(u1.x) * w1 + bf2f(u2.x) * w2 + bf2f(u3.x) * w3;
        a1 += bf2f(u0.y) * w0 + bf2f(u1.y) * w1 + bf2f(u2.y) * w2 + bf2f(u3.y) * w3;
    }
    for (; e < end; e++) {
        int s = col[e];
        float wv = dinv[s];
        ushort2 u = *(const ushort2*)&hc[(size_t)s * CH + 2 * fl];
        a0 += bf2f(u.x) * wv;
        a1 += bf2f(u.y) * wv;
    }
    a0 *= ddst;
    a1 *= ddst;

    if (valid) {
        int f0 = chunk * CH + 2 * fl;
        ushort2 us = *(const ushort2*)&hc[(size_t)nc * CH + 2 * fl];
        float2 bv = *(const float2*)&bias[f0];
        float v0 = fmaxf(a0 + bf2f(us.x) * ddst * ddst + bv.x, 0.f);
        float v1 = fmaxf(a1 + bf2f(us.y) * ddst * ddst + bv.y, 0.f);
        if (OUT_BF16) {
            ushort2 o; o.x = f2bf(v0); o.y = f2bf(v1);
            *(ushort2*)&((unsigned short*)out)[(size_t)nc * F + f0] = o;
        } else {
            float2 o; o.x = v0; o.y = v1;
            *(float2*)&((float*)out)[(size_t)nc * F + f0] = o;
        }
    }
}

extern "C" void kernel_launch(void* const* d_in, const int* in_sizes, int n_in,
                              void* d_out, int out_size, void* d_ws, size_t ws_size,
                              hipStream_t stream) {
    const float* x  = (const float*)d_in[0];   // [N, 256]
    const int* ei   = (const int*)d_in[1];     // [2, E] int32
    const float* W1 = (const float*)d_in[2];   // [256, 256]
    const float* b1 = (const float*)d_in[3];   // [256]
    const float* W2 = (const float*)d_in[4];   // [256, 128]
    const float* b2 = (const float*)d_in[5];   // [128]

    const int DIN = 256;
    const int N = in_sizes[0] / DIN;        // 50000
    const int E = in_sizes[1] / 2;          // 800000
    const int H = in_sizes[3];              // 256
    const int DOUT = in_sizes[5];           // 128

    const int* src = ei;
    const int* dst = ei + E;

    // workspace layout
    char* ws = (char*)d_ws;
    unsigned* deg = (unsigned*)ws;                   ws += (size_t)N * 4;
    float* dinv   = (float*)ws;                      ws += (size_t)N * 4;
    int* rowptr   = (int*)ws;                        ws += (size_t)(N + 4) * 4;
    int* bsum     = (int*)ws;                        ws += 64 * 4;
    int* cursor   = (int*)ws;                        ws += (size_t)N * 4;
    int* col      = (int*)ws;                        ws += (size_t)E * 4;
    unsigned short* xb  = (unsigned short*)ws;       ws += (size_t)N * DIN * 2;
    unsigned short* w1t = (unsigned short*)ws;       ws += (size_t)DIN * H * 2;
    unsigned short* w2t = (unsigned short*)ws;       ws += (size_t)H * DOUT * 2;
    unsigned short* h1b = (unsigned short*)ws;       ws += (size_t)N * H * 2;    // chunk-major [8][N][32]
    unsigned short* y1b = (unsigned short*)ws;       ws += (size_t)N * H * 2;    // node-major [N][256]
    unsigned short* h2b = xb;                        // chunk-major [8][N][16]; xb dead after gemm1
    float* outp = (float*)d_out;

    // ---- CSR build ----
    hipMemsetAsync(deg, 0, (size_t)N * 4, stream);
    degree_kernel<<<(E + 255) / 256, 256, 0, stream>>>(dst, deg, E);
    dinv_kernel<<<(N + 255) / 256, 256, 0, stream>>>(deg, dinv, N);
    {
        int nb = (N + SCAN_CHUNK - 1) / SCAN_CHUNK;
        scan_phase1<<<nb, 256, 0, stream>>>(deg, bsum, N);
        scan_phase2<<<1, 64, 0, stream>>>(bsum, nb);
        scan_phase3<<<nb, 256, 0, stream>>>(deg, bsum, rowptr, cursor, N);
    }
    fill_kernel<<<(E + 255) / 256, 256, 0, stream>>>(src, dst, cursor, col, E);

    // ---- conversions ----
    {
        long n4 = (long)N * DIN / 4;
        convert_x_kernel<<<(int)((n4 + 255) / 256), 256, 0, stream>>>(x, xb, n4);
        convert_wt_kernel<<<(DIN * H + 255) / 256, 256, 0, stream>>>(W1, w1t, DIN, H);
        convert_wt_kernel<<<(H * DOUT + 255) / 256, 256, 0, stream>>>(W2, w2t, H, DOUT);
    }

    // ---- layer 1: h1 = x @ W1 (bf16 MFMA, chunk-major out CH=32) ----
    {
        dim3 grid((N + GBM - 1) / GBM, H / GBN);
        gemm_bf16<32><<<grid, 256, 0, stream>>>(xb, w1t, h1b, N, H, DIN);
    }
    {
        constexpr int NPB1 = (64 / (32 / 2)) * 4;   // 16 nodes/block
        gather_cm_kernel<32, true><<<8 * ((N + NPB1 - 1) / NPB1), 256, 0, stream>>>(
            h1b, rowptr, col, dinv, b1, y1b, N, H);
    }

    // ---- layer 2: h2 = y1 @ W2 (bf16 MFMA, chunk-major out CH=16) ----
    {
        dim3 grid((N + GBM - 1) / GBM, DOUT / GBN);
        gemm_bf16<16><<<grid, 256, 0, stream>>>(y1b, w2t, h2b, N, DOUT, H);
    }
    {
        constexpr int NPB2 = (64 / (16 / 2)) * 4;   // 32 nodes/block
        gather_cm_kernel<16, false><<<8 * ((N + NPB2 - 1) / NPB2), 256, 0, stream>>>(
            h2b, rowptr, col, dinv, b2, outp, N, DOUT);
    }
}